// Round 1
// baseline (225.143 us; speedup 1.0000x reference)
//
#include <hip/hip_runtime.h>
#include <hip/hip_bf16.h>

#define AS1 __attribute__((address_space(1)))
#define AS3 __attribute__((address_space(3)))

typedef __attribute__((ext_vector_type(8))) short bf16x8v;   // 8 bf16 (4 VGPRs)
typedef __attribute__((ext_vector_type(4))) float f32x4;

// ---------------------------------------------------------------------------
// prep: transpose the three 64x64 projection weights to [e][d] (coalesced
// per-lane reads in attn_kernel), convert Wfc to bf16 for the MFMA GEMM.
// ---------------------------------------------------------------------------
__global__ void prep_kernel(const float* __restrict__ Wq, const float* __restrict__ Wk,
                            const float* __restrict__ Wv, const float* __restrict__ Wfc,
                            float* __restrict__ WqT, float* __restrict__ WkT,
                            float* __restrict__ WvT, __hip_bfloat16* __restrict__ Wfcb)
{
  int i = blockIdx.x * blockDim.x + threadIdx.x;
  if (i < 64 * 64) {
    int d = i >> 6, e = i & 63;           // W[d][e]  ->  WT[e][d]
    WqT[e * 64 + d] = Wq[i];
    WkT[e * 64 + d] = Wk[i];
    WvT[e * 64 + d] = Wv[i];
  }
  for (int j = i; j < 1024 * 1024; j += gridDim.x * blockDim.x)
    Wfcb[j] = __float2bfloat16(Wfc[j]);
}

// ---------------------------------------------------------------------------
// attn_kernel: one wave per token, lane = d (0..63). All math f32.
// LDS per wave: xb[1024] f32 (stage buffer, reused q->k->v->attn) +
//               q/k [16][68] f32 (68 = 64+4 pad: 16B-aligned rows, bank-clean)
// ---------------------------------------------------------------------------
__device__ __forceinline__ void project(const float* __restrict__ xin, size_t tb,
                                        const float* __restrict__ wT,
                                        const float* __restrict__ bvec,
                                        float* xb, int lane, float acc[16])
{
  // stage the 1024-float token row into LDS (coalesced float4)
#pragma unroll
  for (int j = 0; j < 4; ++j) {
    float4 t = *(const float4*)(xin + tb + j * 256 + lane * 4);
    *(float4*)(xb + j * 256 + lane * 4) = t;
  }
  asm volatile("s_waitcnt lgkmcnt(0)" ::: "memory"); // wave's LDS writes visible

  float bb = bvec[lane];
#pragma unroll
  for (int h = 0; h < 16; ++h) acc[h] = bb;
  // acc[h] (d=lane) = sum_e x[h*64+e] * W[d][e] ; wT is [e][d] -> coalesced
  for (int e4 = 0; e4 < 16; ++e4) {
    float w0 = wT[(e4 * 4 + 0) * 64 + lane];
    float w1 = wT[(e4 * 4 + 1) * 64 + lane];
    float w2 = wT[(e4 * 4 + 2) * 64 + lane];
    float w3 = wT[(e4 * 4 + 3) * 64 + lane];
#pragma unroll
    for (int h = 0; h < 16; ++h) {
      float4 x4 = *(const float4*)(xb + h * 64 + e4 * 4); // uniform -> broadcast
      acc[h] = fmaf(x4.x, w0, acc[h]);
      acc[h] = fmaf(x4.y, w1, acc[h]);
      acc[h] = fmaf(x4.z, w2, acc[h]);
      acc[h] = fmaf(x4.w, w3, acc[h]);
    }
  }
}

__global__ __launch_bounds__(256) void attn_kernel(
    const float* __restrict__ Vin, const float* __restrict__ Kin,
    const float* __restrict__ Qin,
    const float* __restrict__ WvT, const float* __restrict__ WkT,
    const float* __restrict__ WqT,
    const float* __restrict__ bv, const float* __restrict__ bk,
    const float* __restrict__ bq,
    __hip_bfloat16* __restrict__ Xout)
{
  __shared__ float xbuf[4][1024];
  __shared__ float qkbuf[4][2][16][68];
  const int wid = threadIdx.x >> 6, lane = threadIdx.x & 63;
  const int token = blockIdx.x * 4 + wid;            // 4096 blocks * 4 waves
  const size_t tb = (size_t)token * 1024;
  float* xb = xbuf[wid];

  float qacc[16], kacc[16], vacc[16];

  project(Qin, tb, WqT, bq, xb, lane, qacc);
#pragma unroll
  for (int h = 0; h < 16; ++h) qkbuf[wid][0][h][lane] = qacc[h];

  project(Kin, tb, WkT, bk, xb, lane, kacc);
#pragma unroll
  for (int h = 0; h < 16; ++h) qkbuf[wid][1][h][lane] = kacc[h];

  project(Vin, tb, WvT, bv, xb, lane, vacc);
  asm volatile("s_waitcnt lgkmcnt(0)" ::: "memory");

  // energy[h][g] = sum_d q[h][d]*k[g][d] ; lane handles h=lane&15, g=gb..gb+3
  const float (*qrow)[68] = qkbuf[wid][0];
  const float (*krow)[68] = qkbuf[wid][1];
  const int h = lane & 15;
  const int gb = (lane >> 4) * 4;
  float ev[4] = {0.f, 0.f, 0.f, 0.f};
  for (int d4 = 0; d4 < 16; ++d4) {
    float4 q4 = *(const float4*)(&qrow[h][d4 * 4]);
#pragma unroll
    for (int p = 0; p < 4; ++p) {
      float4 k4 = *(const float4*)(&krow[gb + p][d4 * 4]);
      ev[p] += q4.x * k4.x + q4.y * k4.y + q4.z * k4.z + q4.w * k4.w;
    }
  }
  // softmax over g (16 values spread over lanes {l, l^16, l^32, l^48})
  const float scale = 0.125f;   // 1/sqrt(64)
  float mx = fmaxf(fmaxf(ev[0], ev[1]), fmaxf(ev[2], ev[3])) * scale;
  mx = fmaxf(mx, __shfl_xor(mx, 16));
  mx = fmaxf(mx, __shfl_xor(mx, 32));
  float pr[4], ssum = 0.f;
#pragma unroll
  for (int p = 0; p < 4; ++p) { pr[p] = __expf(ev[p] * scale - mx); ssum += pr[p]; }
  ssum += __shfl_xor(ssum, 16);
  ssum += __shfl_xor(ssum, 32);
  const float inv = 1.0f / ssum;

  // attn into xb (reuse), then PV with v in registers
#pragma unroll
  for (int p = 0; p < 4; ++p) xb[h * 16 + gb + p] = pr[p] * inv;
  asm volatile("s_waitcnt lgkmcnt(0)" ::: "memory");

#pragma unroll
  for (int hh = 0; hh < 16; ++hh) {
    float o = 0.f;
#pragma unroll
    for (int g4 = 0; g4 < 4; ++g4) {
      float4 a4 = *(const float4*)(xb + hh * 16 + g4 * 4); // uniform broadcast
      o += a4.x * vacc[g4 * 4 + 0] + a4.y * vacc[g4 * 4 + 1] +
           a4.z * vacc[g4 * 4 + 2] + a4.w * vacc[g4 * 4 + 3];
    }
    Xout[tb + hh * 64 + lane] = __float2bfloat16(o);
  }
}

// ---------------------------------------------------------------------------
// gemm_kernel: C[16384][1024] = X[16384][1024](bf16) @ Wfc[1024][1024]^T + bfc
// m97 structure: 128x128 tile, BK=64, 4 waves (2x2), global_load_lds w=16,
// both-sides XOR swizzle (pre-swizzled global source + swizzled ds_read).
// ---------------------------------------------------------------------------
__global__ __launch_bounds__(256) void gemm_kernel(
    const __hip_bfloat16* __restrict__ A,   // X    [16384][1024] row-major
    const __hip_bfloat16* __restrict__ B,   // Wfc  [1024][1024]  (row n, col k)
    const float* __restrict__ bias, float* __restrict__ C)
{
  constexpr int K = 1024, N = 1024;
  __shared__ __hip_bfloat16 Asm[128 * 64];  // [row][64] bf16, 128B rows
  __shared__ __hip_bfloat16 Bsm[128 * 64];
  const int tid = threadIdx.x, wid = tid >> 6, lane = tid & 63;
  const int bm = blockIdx.x >> 3, bn = blockIdx.x & 7;
  const int m0 = bm * 128, n0 = bn * 128;
  const int wr = wid >> 1, wc = wid & 1;    // 2x2 waves -> 64x64 each

  f32x4 acc[4][4];
#pragma unroll
  for (int i = 0; i < 4; ++i)
#pragma unroll
    for (int j = 0; j < 4; ++j) acc[i][j] = (f32x4){0.f, 0.f, 0.f, 0.f};

  const int lrow = lane >> 3;                    // row within 8-row call group
  const int gcol = ((lane & 7) ^ lrow) * 8;      // pre-swizzled source column

  for (int kt = 0; kt < K / 64; ++kt) {
    const int k0 = kt * 64;
    __syncthreads();                             // prev compute done
#pragma unroll
    for (int c = 0; c < 4; ++c) {
      const int ca = wid * 4 + c;                // 16 calls total per operand
      const int row = ca * 8 + lrow;
      __builtin_amdgcn_global_load_lds(
          (const AS1 void*)(A + (size_t)(m0 + row) * K + k0 + gcol),
          (AS3 void*)((char*)Asm + ca * 1024), 16, 0, 0);
      __builtin_amdgcn_global_load_lds(
          (const AS1 void*)(B + (size_t)(n0 + row) * K + k0 + gcol),
          (AS3 void*)((char*)Bsm + ca * 1024), 16, 0, 0);
    }
    asm volatile("s_waitcnt vmcnt(0)" ::: "memory");
    __syncthreads();

#pragma unroll
    for (int ks = 0; ks < 2; ++ks) {
      bf16x8v af[4], bfr[4];
#pragma unroll
      for (int mi = 0; mi < 4; ++mi) {
        const int arow = wr * 64 + mi * 16 + (lane & 15);
        const int slot = (ks * 4 + (lane >> 4)) ^ (arow & 7); // inverse swizzle
        af[mi] = *(const bf16x8v*)((const char*)Asm + arow * 128 + slot * 16);
      }
#pragma unroll
      for (int ni = 0; ni < 4; ++ni) {
        const int brow = wc * 64 + ni * 16 + (lane & 15);
        const int slot = (ks * 4 + (lane >> 4)) ^ (brow & 7);
        bfr[ni] = *(const bf16x8v*)((const char*)Bsm + brow * 128 + slot * 16);
      }
#pragma unroll
      for (int mi = 0; mi < 4; ++mi)
#pragma unroll
        for (int ni = 0; ni < 4; ++ni)
          acc[mi][ni] = __builtin_amdgcn_mfma_f32_16x16x32_bf16(
              af[mi], bfr[ni], acc[mi][ni], 0, 0, 0);
    }
  }

  // epilogue: D layout row=(lane>>4)*4+j, col=lane&15  [verified m89/m91]
#pragma unroll
  for (int mi = 0; mi < 4; ++mi) {
    const int r0 = m0 + wr * 64 + mi * 16 + (lane >> 4) * 4;
#pragma unroll
    for (int ni = 0; ni < 4; ++ni) {
      const int c = n0 + wc * 64 + ni * 16 + (lane & 15);
      const float bs = bias[c];
#pragma unroll
      for (int j = 0; j < 4; ++j)
        C[(size_t)(r0 + j) * N + c] = acc[mi][ni][j] + bs;
    }
  }
}

// ---------------------------------------------------------------------------
extern "C" void kernel_launch(void* const* d_in, const int* in_sizes, int n_in,
                              void* d_out, int out_size, void* d_ws, size_t ws_size,
                              hipStream_t stream)
{
  const float* value = (const float*)d_in[0];
  const float* key   = (const float*)d_in[1];
  const float* query = (const float*)d_in[2];
  const float* Wv  = (const float*)d_in[3];
  const float* bv  = (const float*)d_in[4];
  const float* Wk  = (const float*)d_in[5];
  const float* bk  = (const float*)d_in[6];
  const float* Wq  = (const float*)d_in[7];
  const float* bq  = (const float*)d_in[8];
  const float* Wfc = (const float*)d_in[9];
  const float* bfc = (const float*)d_in[10];
  float* out = (float*)d_out;

  // workspace layout: X bf16 (32 MiB) | Wfc bf16 (2 MiB) | WqT/WkT/WvT (48 KiB)
  char* ws = (char*)d_ws;
  __hip_bfloat16* Xb   = (__hip_bfloat16*)ws;
  __hip_bfloat16* Wfcb = (__hip_bfloat16*)(ws + (33554432));
  float* WqT = (float*)(ws + 33554432 + 2097152);
  float* WkT = WqT + 4096;
  float* WvT = WkT + 4096;

  prep_kernel<<<4096, 256, 0, stream>>>(Wq, Wk, Wv, Wfc, WqT, WkT, WvT, Wfcb);
  attn_kernel<<<4096, 256, 0, stream>>>(value, key, query, WvT, WkT, WqT,
                                        bv, bk, bq, Xb);
  gemm_kernel<<<1024, 256, 0, stream>>>(Xb, Wfcb, bfc, out);
}

// Round 2
// 118.865 us; speedup vs baseline: 1.8941x; 1.8941x over previous
//
#include <hip/hip_runtime.h>
#include <hip/hip_bf16.h>

#define AS1 __attribute__((address_space(1)))
#define AS3 __attribute__((address_space(3)))

typedef __attribute__((ext_vector_type(8))) short bf16x8v;   // 8 bf16 (4 VGPRs)
typedef __attribute__((ext_vector_type(4))) short bf16x4v;   // 4 bf16 (2 VGPRs)
typedef __attribute__((ext_vector_type(4))) float f32x4;

__device__ __forceinline__ short f2bf(float f) {
  __hip_bfloat16 h = __float2bfloat16(f);          // RNE
  return *reinterpret_cast<short*>(&h);
}
__device__ __forceinline__ bf16x4v cvt4(f32x4 v) {
  bf16x4v r; r[0]=f2bf(v[0]); r[1]=f2bf(v[1]); r[2]=f2bf(v[2]); r[3]=f2bf(v[3]);
  return r;
}
__device__ __forceinline__ bf16x8v cvt8(float4 a, float4 b) {
  bf16x8v r;
  r[0]=f2bf(a.x); r[1]=f2bf(a.y); r[2]=f2bf(a.z); r[3]=f2bf(a.w);
  r[4]=f2bf(b.x); r[5]=f2bf(b.y); r[6]=f2bf(b.z); r[7]=f2bf(b.w);
  return r;
}

// ---------------------------------------------------------------------------
// prep: bf16 copies of Wq/Wk/Wv (row-major, for direct fragment loads) + Wfc.
// ---------------------------------------------------------------------------
__global__ void prep_kernel(const float* __restrict__ Wq, const float* __restrict__ Wk,
                            const float* __restrict__ Wv, const float* __restrict__ Wfc,
                            __hip_bfloat16* __restrict__ Wqb, __hip_bfloat16* __restrict__ Wkb,
                            __hip_bfloat16* __restrict__ Wvb, __hip_bfloat16* __restrict__ Wfcb)
{
  int i = blockIdx.x * blockDim.x + threadIdx.x;
  if (i < 64 * 64) {
    Wqb[i] = __float2bfloat16(Wq[i]);
    Wkb[i] = __float2bfloat16(Wk[i]);
    Wvb[i] = __float2bfloat16(Wv[i]);
  }
  for (int j = i; j < 1024 * 1024; j += gridDim.x * blockDim.x)
    Wfcb[j] = __float2bfloat16(Wfc[j]);
}

// ---------------------------------------------------------------------------
// attn_kernel: 1 wave = 4 tokens, all-MFMA, zero LDS / zero barriers.
//   qT = Wq@x^T, kT = Wk@x^T   (16x16x32, C-layout == E' operand layouts)
//   E' = K@Q^T (16x16x16, 4 k-steps) -> softmax lane-local -> P == PV A-frag
//   v  = x@Wv^T (16x16x32, C-layout == PV B-frag)
//   O  = P@v   (16x16x16)
// ---------------------------------------------------------------------------
__global__ __launch_bounds__(256, 2) void attn_kernel(
    const float* __restrict__ Vin, const float* __restrict__ Kin,
    const float* __restrict__ Qin,
    const __hip_bfloat16* __restrict__ Wvb, const __hip_bfloat16* __restrict__ Wkb,
    const __hip_bfloat16* __restrict__ Wqb,
    const float* __restrict__ bv, const float* __restrict__ bk,
    const float* __restrict__ bq,
    __hip_bfloat16* __restrict__ Xout)
{
  const int wid = threadIdx.x >> 6, lane = threadIdx.x & 63;
  const int lo = lane & 15, hi = lane >> 4;
  const int tok0 = (blockIdx.x * 4 + wid) * 4;

  // weight fragments, once per wave (L1/L2-resident, 16 B per lane each)
  bf16x8v wqf[4][2], wkf[4][2], wvf[4][2];
#pragma unroll
  for (int i = 0; i < 4; ++i)
#pragma unroll
    for (int ks = 0; ks < 2; ++ks) {
      const int off = (i * 16 + lo) * 64 + ks * 32 + hi * 8;
      wqf[i][ks] = *(const bf16x8v*)(Wqb + off);
      wkf[i][ks] = *(const bf16x8v*)(Wkb + off);
      wvf[i][ks] = *(const bf16x8v*)(Wvb + off);
    }
  float4 bq4[4], bk4[4]; float bvv[4];
#pragma unroll
  for (int i = 0; i < 4; ++i) {
    bq4[i] = *(const float4*)(bq + i * 16 + hi * 4);
    bk4[i] = *(const float4*)(bk + i * 16 + hi * 4);
    bvv[i] = bv[i * 16 + lo];
  }

#pragma unroll 1
  for (int tl = 0; tl < 4; ++tl) {
    const size_t tb = (size_t)(tok0 + tl) * 1024;
    // x fragments: lane reads row h=lo, 8 consecutive d at ks*32+hi*8 (f32)
    const float* qp = Qin + tb + lo * 64 + hi * 8;
    const float* kp = Kin + tb + lo * 64 + hi * 8;
    const float* vp = Vin + tb + lo * 64 + hi * 8;
    float4 qa0 = *(const float4*)(qp),      qb0 = *(const float4*)(qp + 4);
    float4 qa1 = *(const float4*)(qp + 32), qb1 = *(const float4*)(qp + 36);
    float4 ka0 = *(const float4*)(kp),      kb0 = *(const float4*)(kp + 4);
    float4 ka1 = *(const float4*)(kp + 32), kb1 = *(const float4*)(kp + 36);
    float4 va0 = *(const float4*)(vp),      vb0 = *(const float4*)(vp + 4);
    float4 va1 = *(const float4*)(vp + 32), vb1 = *(const float4*)(vp + 36);
    bf16x8v xq[2] = { cvt8(qa0, qb0), cvt8(qa1, qb1) };
    bf16x8v xk[2] = { cvt8(ka0, kb0), cvt8(ka1, kb1) };
    bf16x8v xv[2] = { cvt8(va0, vb0), cvt8(va1, vb1) };

    // qT[d][h], kT[d][h]: per d-block i, C row = d = i*16+hi*4+j, col = h = lo
    f32x4 qt[4], kt[4], vc[4];
#pragma unroll
    for (int i = 0; i < 4; ++i) {
      f32x4 aq = { bq4[i].x, bq4[i].y, bq4[i].z, bq4[i].w };
      aq = __builtin_amdgcn_mfma_f32_16x16x32_bf16(wqf[i][0], xq[0], aq, 0, 0, 0);
      aq = __builtin_amdgcn_mfma_f32_16x16x32_bf16(wqf[i][1], xq[1], aq, 0, 0, 0);
      qt[i] = aq;
      f32x4 ak = { bk4[i].x, bk4[i].y, bk4[i].z, bk4[i].w };
      ak = __builtin_amdgcn_mfma_f32_16x16x32_bf16(wkf[i][0], xk[0], ak, 0, 0, 0);
      ak = __builtin_amdgcn_mfma_f32_16x16x32_bf16(wkf[i][1], xk[1], ak, 0, 0, 0);
      kt[i] = ak;
    }
    // v[g][dv]: per dv-block i, C row = g = hi*4+j, col = dv = i*16+lo
#pragma unroll
    for (int i = 0; i < 4; ++i) {
      f32x4 av = { bvv[i], bvv[i], bvv[i], bvv[i] };
      av = __builtin_amdgcn_mfma_f32_16x16x32_bf16(xv[0], wvf[i][0], av, 0, 0, 0);
      av = __builtin_amdgcn_mfma_f32_16x16x32_bf16(xv[1], wvf[i][1], av, 0, 0, 0);
      vc[i] = av;
    }

    // E' = K@Q^T, accumulated over 4 d-blocks (K=16 each).
    // e[j] = E[h=lo][g=hi*4+j]
    f32x4 e = { 0.f, 0.f, 0.f, 0.f };
#pragma unroll
    for (int di = 0; di < 4; ++di)
      e = __builtin_amdgcn_mfma_f32_16x16x16bf16_1k(cvt4(kt[di]), cvt4(qt[di]), e, 0, 0, 0);

    // softmax over g: in-lane 4 + lanes l^16, l^32 (scale 1/sqrt(64)=1/8)
    float mx = fmaxf(fmaxf(e[0], e[1]), fmaxf(e[2], e[3]));
    mx = fmaxf(mx, __shfl_xor(mx, 16));
    mx = fmaxf(mx, __shfl_xor(mx, 32));
    float p0 = __expf((e[0] - mx) * 0.125f);
    float p1 = __expf((e[1] - mx) * 0.125f);
    float p2 = __expf((e[2] - mx) * 0.125f);
    float p3 = __expf((e[3] - mx) * 0.125f);
    float s = p0 + p1 + p2 + p3;
    s += __shfl_xor(s, 16);
    s += __shfl_xor(s, 32);
    const float inv = 1.0f / s;
    bf16x4v pa;
    pa[0] = f2bf(p0 * inv); pa[1] = f2bf(p1 * inv);
    pa[2] = f2bf(p2 * inv); pa[3] = f2bf(p3 * inv);

    // O = P @ v ; D row = h = hi*4+j, col = dv = ni*16+lo
    __hip_bfloat16* xo = Xout + tb + (size_t)hi * 4 * 64 + lo;
#pragma unroll
    for (int ni = 0; ni < 4; ++ni) {
      f32x4 z = { 0.f, 0.f, 0.f, 0.f };
      z = __builtin_amdgcn_mfma_f32_16x16x16bf16_1k(pa, cvt4(vc[ni]), z, 0, 0, 0);
#pragma unroll
      for (int j = 0; j < 4; ++j)
        xo[j * 64 + ni * 16] = __float2bfloat16(z[j]);
    }
  }
}

// ---------------------------------------------------------------------------
// gemm_kernel: C[16384][1024] = X(bf16) @ Wfc(bf16)^T + bfc   (unchanged)
// ---------------------------------------------------------------------------
__global__ __launch_bounds__(256) void gemm_kernel(
    const __hip_bfloat16* __restrict__ A,
    const __hip_bfloat16* __restrict__ B,
    const float* __restrict__ bias, float* __restrict__ C)
{
  constexpr int K = 1024, N = 1024;
  __shared__ __hip_bfloat16 Asm[128 * 64];
  __shared__ __hip_bfloat16 Bsm[128 * 64];
  const int tid = threadIdx.x, wid = tid >> 6, lane = tid & 63;
  const int bm = blockIdx.x >> 3, bn = blockIdx.x & 7;
  const int m0 = bm * 128, n0 = bn * 128;
  const int wr = wid >> 1, wc = wid & 1;

  f32x4 acc[4][4];
#pragma unroll
  for (int i = 0; i < 4; ++i)
#pragma unroll
    for (int j = 0; j < 4; ++j) acc[i][j] = (f32x4){0.f, 0.f, 0.f, 0.f};

  const int lrow = lane >> 3;
  const int gcol = ((lane & 7) ^ lrow) * 8;

  for (int kt = 0; kt < K / 64; ++kt) {
    const int k0 = kt * 64;
    __syncthreads();
#pragma unroll
    for (int c = 0; c < 4; ++c) {
      const int ca = wid * 4 + c;
      const int row = ca * 8 + lrow;
      __builtin_amdgcn_global_load_lds(
          (const AS1 void*)(A + (size_t)(m0 + row) * K + k0 + gcol),
          (AS3 void*)((char*)Asm + ca * 1024), 16, 0, 0);
      __builtin_amdgcn_global_load_lds(
          (const AS1 void*)(B + (size_t)(n0 + row) * K + k0 + gcol),
          (AS3 void*)((char*)Bsm + ca * 1024), 16, 0, 0);
    }
    asm volatile("s_waitcnt vmcnt(0)" ::: "memory");
    __syncthreads();

#pragma unroll
    for (int ks = 0; ks < 2; ++ks) {
      bf16x8v af[4], bfr[4];
#pragma unroll
      for (int mi = 0; mi < 4; ++mi) {
        const int arow = wr * 64 + mi * 16 + (lane & 15);
        const int slot = (ks * 4 + (lane >> 4)) ^ (arow & 7);
        af[mi] = *(const bf16x8v*)((const char*)Asm + arow * 128 + slot * 16);
      }
#pragma unroll
      for (int ni = 0; ni < 4; ++ni) {
        const int brow = wc * 64 + ni * 16 + (lane & 15);
        const int slot = (ks * 4 + (lane >> 4)) ^ (brow & 7);
        bfr[ni] = *(const bf16x8v*)((const char*)Bsm + brow * 128 + slot * 16);
      }
#pragma unroll
      for (int mi = 0; mi < 4; ++mi)
#pragma unroll
        for (int ni = 0; ni < 4; ++ni)
          acc[mi][ni] = __builtin_amdgcn_mfma_f32_16x16x32_bf16(
              af[mi], bfr[ni], acc[mi][ni], 0, 0, 0);
    }
  }

#pragma unroll
  for (int mi = 0; mi < 4; ++mi) {
    const int r0 = m0 + wr * 64 + mi * 16 + (lane >> 4) * 4;
#pragma unroll
    for (int ni = 0; ni < 4; ++ni) {
      const int c = n0 + wc * 64 + ni * 16 + (lane & 15);
      const float bs = bias[c];
#pragma unroll
      for (int j = 0; j < 4; ++j)
        C[(size_t)(r0 + j) * N + c] = acc[mi][ni][j] + bs;
    }
  }
}

// ---------------------------------------------------------------------------
extern "C" void kernel_launch(void* const* d_in, const int* in_sizes, int n_in,
                              void* d_out, int out_size, void* d_ws, size_t ws_size,
                              hipStream_t stream)
{
  const float* value = (const float*)d_in[0];
  const float* key   = (const float*)d_in[1];
  const float* query = (const float*)d_in[2];
  const float* Wv  = (const float*)d_in[3];
  const float* bv  = (const float*)d_in[4];
  const float* Wk  = (const float*)d_in[5];
  const float* bk  = (const float*)d_in[6];
  const float* Wq  = (const float*)d_in[7];
  const float* bq  = (const float*)d_in[8];
  const float* Wfc = (const float*)d_in[9];
  const float* bfc = (const float*)d_in[10];
  float* out = (float*)d_out;

  char* ws = (char*)d_ws;
  __hip_bfloat16* Xb   = (__hip_bfloat16*)ws;                          // 32 MiB
  __hip_bfloat16* Wfcb = (__hip_bfloat16*)(ws + 33554432);             // 2 MiB
  __hip_bfloat16* Wqb  = (__hip_bfloat16*)(ws + 33554432 + 2097152);   // 8 KiB
  __hip_bfloat16* Wkb  = Wqb + 4096;
  __hip_bfloat16* Wvb  = Wkb + 4096;

  prep_kernel<<<4096, 256, 0, stream>>>(Wq, Wk, Wv, Wfc, Wqb, Wkb, Wvb, Wfcb);
  attn_kernel<<<1024, 256, 0, stream>>>(value, key, query, Wvb, Wkb, Wqb,
                                        bv, bk, bq, Xb);
  gemm_kernel<<<1024, 256, 0, stream>>>(Xb, Wfcb, bfc, out);
}

// Round 3
// 116.628 us; speedup vs baseline: 1.9304x; 1.0192x over previous
//
#include <hip/hip_runtime.h>
#include <hip/hip_bf16.h>

#define AS1 __attribute__((address_space(1)))
#define AS3 __attribute__((address_space(3)))

typedef __attribute__((ext_vector_type(8))) short bf16x8v;   // 8 bf16 (4 VGPRs)
typedef __attribute__((ext_vector_type(4))) short bf16x4v;   // 4 bf16 (2 VGPRs)
typedef __attribute__((ext_vector_type(4))) float f32x4;

#define MFMA32 __builtin_amdgcn_mfma_f32_16x16x32_bf16
#define MFMA16 __builtin_amdgcn_mfma_f32_16x16x16bf16_1k

__device__ __forceinline__ short f2bf(float f) {
  __hip_bfloat16 h = __float2bfloat16(f);          // RNE
  return *reinterpret_cast<short*>(&h);
}
__device__ __forceinline__ bf16x4v cvt4(f32x4 v) {
  bf16x4v r; r[0]=f2bf(v[0]); r[1]=f2bf(v[1]); r[2]=f2bf(v[2]); r[3]=f2bf(v[3]);
  return r;
}
__device__ __forceinline__ bf16x8v cvt8(float4 a, float4 b) {
  bf16x8v r;
  r[0]=f2bf(a.x); r[1]=f2bf(a.y); r[2]=f2bf(a.z); r[3]=f2bf(a.w);
  r[4]=f2bf(b.x); r[5]=f2bf(b.y); r[6]=f2bf(b.z); r[7]=f2bf(b.w);
  return r;
}

// ---------------------------------------------------------------------------
// prep: bf16 copies of Wq/Wk/Wv (row-major, for direct fragment loads) + Wfc.
// ---------------------------------------------------------------------------
__global__ void prep_kernel(const float* __restrict__ Wq, const float* __restrict__ Wk,
                            const float* __restrict__ Wv, const float* __restrict__ Wfc,
                            __hip_bfloat16* __restrict__ Wqb, __hip_bfloat16* __restrict__ Wkb,
                            __hip_bfloat16* __restrict__ Wvb, __hip_bfloat16* __restrict__ Wfcb)
{
  int i = blockIdx.x * blockDim.x + threadIdx.x;
  if (i < 64 * 64) {
    Wqb[i] = __float2bfloat16(Wq[i]);
    Wkb[i] = __float2bfloat16(Wk[i]);
    Wvb[i] = __float2bfloat16(Wv[i]);
  }
  for (int j = i; j < 1024 * 1024; j += gridDim.x * blockDim.x)
    Wfcb[j] = __float2bfloat16(Wfc[j]);
}

// ---------------------------------------------------------------------------
// attn_kernel: 1 wave = 4 tokens, all-MFMA, zero LDS, software-pipelined:
// token t+1's 12 float4 loads are issued before token t's compute (ping-pong
// register buffers A/B) so one token's loads are always in flight.
// ---------------------------------------------------------------------------
struct TokL {
  float4 qa0, qb0, qa1, qb1;
  float4 ka0, kb0, ka1, kb1;
  float4 va0, vb0, va1, vb1;
};

__global__ __launch_bounds__(256, 2) void attn_kernel(
    const float* __restrict__ Vin, const float* __restrict__ Kin,
    const float* __restrict__ Qin,
    const __hip_bfloat16* __restrict__ Wvb, const __hip_bfloat16* __restrict__ Wkb,
    const __hip_bfloat16* __restrict__ Wqb,
    const float* __restrict__ bv, const float* __restrict__ bk,
    const float* __restrict__ bq,
    __hip_bfloat16* __restrict__ Xout)
{
  const int wid = threadIdx.x >> 6, lane = threadIdx.x & 63;
  const int lo = lane & 15, hi = lane >> 4;
  const int tok0 = (blockIdx.x * 4 + wid) * 4;
  const int xoff = lo * 64 + hi * 8;

  // weight fragments, once per wave (L1/L2-resident, 16 B per lane each)
  bf16x8v wqf[4][2], wkf[4][2], wvf[4][2];
#pragma unroll
  for (int i = 0; i < 4; ++i)
#pragma unroll
    for (int ks = 0; ks < 2; ++ks) {
      const int off = (i * 16 + lo) * 64 + ks * 32 + hi * 8;
      wqf[i][ks] = *(const bf16x8v*)(Wqb + off);
      wkf[i][ks] = *(const bf16x8v*)(Wkb + off);
      wvf[i][ks] = *(const bf16x8v*)(Wvb + off);
    }
  float4 bq4[4], bk4[4]; float bvv[4];
#pragma unroll
  for (int i = 0; i < 4; ++i) {
    bq4[i] = *(const float4*)(bq + i * 16 + hi * 4);
    bk4[i] = *(const float4*)(bk + i * 16 + hi * 4);
    bvv[i] = bv[i * 16 + lo];
  }

  auto load_tok = [&](int tl, TokL& L) {
    const size_t tb = (size_t)(tok0 + tl) * 1024;
    const float* qp = Qin + tb + xoff;
    const float* kp = Kin + tb + xoff;
    const float* vp = Vin + tb + xoff;
    L.qa0 = *(const float4*)(qp);      L.qb0 = *(const float4*)(qp + 4);
    L.qa1 = *(const float4*)(qp + 32); L.qb1 = *(const float4*)(qp + 36);
    L.ka0 = *(const float4*)(kp);      L.kb0 = *(const float4*)(kp + 4);
    L.ka1 = *(const float4*)(kp + 32); L.kb1 = *(const float4*)(kp + 36);
    L.va0 = *(const float4*)(vp);      L.vb0 = *(const float4*)(vp + 4);
    L.va1 = *(const float4*)(vp + 32); L.vb1 = *(const float4*)(vp + 36);
  };

  auto compute_tok = [&](int tl, const TokL& L) {
    const size_t tb = (size_t)(tok0 + tl) * 1024;
    bf16x8v xq0 = cvt8(L.qa0, L.qb0), xq1 = cvt8(L.qa1, L.qb1);
    bf16x8v xk0 = cvt8(L.ka0, L.kb0), xk1 = cvt8(L.ka1, L.kb1);

    // qT[d][h], kT[d][h]: per d-block i, C row = d = i*16+hi*4+j, col = h = lo
    f32x4 qt[4], kt[4];
#pragma unroll
    for (int i = 0; i < 4; ++i) {
      f32x4 aq = { bq4[i].x, bq4[i].y, bq4[i].z, bq4[i].w };
      aq = MFMA32(wqf[i][0], xq0, aq, 0, 0, 0);
      aq = MFMA32(wqf[i][1], xq1, aq, 0, 0, 0);
      qt[i] = aq;
      f32x4 ak = { bk4[i].x, bk4[i].y, bk4[i].z, bk4[i].w };
      ak = MFMA32(wkf[i][0], xk0, ak, 0, 0, 0);
      ak = MFMA32(wkf[i][1], xk1, ak, 0, 0, 0);
      kt[i] = ak;
    }

    // E' = K@Q^T over 4 d-blocks, two independent 2-deep chains
    f32x4 ea = { 0.f, 0.f, 0.f, 0.f }, eb = { 0.f, 0.f, 0.f, 0.f };
    ea = MFMA16(cvt4(kt[0]), cvt4(qt[0]), ea, 0, 0, 0);
    eb = MFMA16(cvt4(kt[1]), cvt4(qt[1]), eb, 0, 0, 0);
    ea = MFMA16(cvt4(kt[2]), cvt4(qt[2]), ea, 0, 0, 0);
    eb = MFMA16(cvt4(kt[3]), cvt4(qt[3]), eb, 0, 0, 0);
    f32x4 e = ea + eb;   // e[j] = E[h=lo][g=hi*4+j]

    // softmax over g: in-lane 4 + lanes l^16, l^32 (scale 1/8)
    float mx = fmaxf(fmaxf(e[0], e[1]), fmaxf(e[2], e[3]));
    mx = fmaxf(mx, __shfl_xor(mx, 16));
    mx = fmaxf(mx, __shfl_xor(mx, 32));
    float p0 = __expf((e[0] - mx) * 0.125f);
    float p1 = __expf((e[1] - mx) * 0.125f);
    float p2 = __expf((e[2] - mx) * 0.125f);
    float p3 = __expf((e[3] - mx) * 0.125f);
    float s = p0 + p1 + p2 + p3;
    s += __shfl_xor(s, 16);
    s += __shfl_xor(s, 32);
    const float inv = 1.0f / s;
    bf16x4v pa;
    pa[0] = f2bf(p0 * inv); pa[1] = f2bf(p1 * inv);
    pa[2] = f2bf(p2 * inv); pa[3] = f2bf(p3 * inv);

    // v = x@Wv^T (deferred: overlaps softmax VALU); row g=hi*4+j, col dv=i*16+lo
    bf16x8v xv0 = cvt8(L.va0, L.vb0), xv1 = cvt8(L.va1, L.vb1);
    f32x4 vc[4];
#pragma unroll
    for (int i = 0; i < 4; ++i) {
      f32x4 av = { bvv[i], bvv[i], bvv[i], bvv[i] };
      av = MFMA32(xv0, wvf[i][0], av, 0, 0, 0);
      av = MFMA32(xv1, wvf[i][1], av, 0, 0, 0);
      vc[i] = av;
    }

    // O = P @ v ; D row = h = hi*4+j, col = dv = ni*16+lo
    __hip_bfloat16* xo = Xout + tb + (size_t)hi * 4 * 64 + lo;
#pragma unroll
    for (int ni = 0; ni < 4; ++ni) {
      f32x4 z = { 0.f, 0.f, 0.f, 0.f };
      z = MFMA16(pa, cvt4(vc[ni]), z, 0, 0, 0);
#pragma unroll
      for (int j = 0; j < 4; ++j)
        xo[j * 64 + ni * 16] = __float2bfloat16(z[j]);
    }
  };

  // depth-1 software pipeline over 4 tokens (ping-pong A/B)
  TokL A, B;
  load_tok(0, A);
  load_tok(1, B);
  compute_tok(0, A);
  load_tok(2, A);
  compute_tok(1, B);
  load_tok(3, B);
  compute_tok(2, A);
  compute_tok(3, B);
}

// ---------------------------------------------------------------------------
// gemm_kernel: C[16384][1024] = X(bf16) @ Wfc(bf16)^T + bfc   (unchanged)
// ---------------------------------------------------------------------------
__global__ __launch_bounds__(256) void gemm_kernel(
    const __hip_bfloat16* __restrict__ A,
    const __hip_bfloat16* __restrict__ B,
    const float* __restrict__ bias, float* __restrict__ C)
{
  constexpr int K = 1024, N = 1024;
  __shared__ __hip_bfloat16 Asm[128 * 64];
  __shared__ __hip_bfloat16 Bsm[128 * 64];
  const int tid = threadIdx.x, wid = tid >> 6, lane = tid & 63;
  const int bm = blockIdx.x >> 3, bn = blockIdx.x & 7;
  const int m0 = bm * 128, n0 = bn * 128;
  const int wr = wid >> 1, wc = wid & 1;

  f32x4 acc[4][4];
#pragma unroll
  for (int i = 0; i < 4; ++i)
#pragma unroll
    for (int j = 0; j < 4; ++j) acc[i][j] = (f32x4){0.f, 0.f, 0.f, 0.f};

  const int lrow = lane >> 3;
  const int gcol = ((lane & 7) ^ lrow) * 8;

  for (int kt = 0; kt < K / 64; ++kt) {
    const int k0 = kt * 64;
    __syncthreads();
#pragma unroll
    for (int c = 0; c < 4; ++c) {
      const int ca = wid * 4 + c;
      const int row = ca * 8 + lrow;
      __builtin_amdgcn_global_load_lds(
          (const AS1 void*)(A + (size_t)(m0 + row) * K + k0 + gcol),
          (AS3 void*)((char*)Asm + ca * 1024), 16, 0, 0);
      __builtin_amdgcn_global_load_lds(
          (const AS1 void*)(B + (size_t)(n0 + row) * K + k0 + gcol),
          (AS3 void*)((char*)Bsm + ca * 1024), 16, 0, 0);
    }
    asm volatile("s_waitcnt vmcnt(0)" ::: "memory");
    __syncthreads();

#pragma unroll
    for (int ks = 0; ks < 2; ++ks) {
      bf16x8v af[4], bfr[4];
#pragma unroll
      for (int mi = 0; mi < 4; ++mi) {
        const int arow = wr * 64 + mi * 16 + (lane & 15);
        const int slot = (ks * 4 + (lane >> 4)) ^ (arow & 7);
        af[mi] = *(const bf16x8v*)((const char*)Asm + arow * 128 + slot * 16);
      }
#pragma unroll
      for (int ni = 0; ni < 4; ++ni) {
        const int brow = wc * 64 + ni * 16 + (lane & 15);
        const int slot = (ks * 4 + (lane >> 4)) ^ (brow & 7);
        bfr[ni] = *(const bf16x8v*)((const char*)Bsm + brow * 128 + slot * 16);
      }
#pragma unroll
      for (int mi = 0; mi < 4; ++mi)
#pragma unroll
        for (int ni = 0; ni < 4; ++ni)
          acc[mi][ni] = __builtin_amdgcn_mfma_f32_16x16x32_bf16(
              af[mi], bfr[ni], acc[mi][ni], 0, 0, 0);
    }
  }

#pragma unroll
  for (int mi = 0; mi < 4; ++mi) {
    const int r0 = m0 + wr * 64 + mi * 16 + (lane >> 4) * 4;
#pragma unroll
    for (int ni = 0; ni < 4; ++ni) {
      const int c = n0 + wc * 64 + ni * 16 + (lane & 15);
      const float bs = bias[c];
#pragma unroll
      for (int j = 0; j < 4; ++j)
        C[(size_t)(r0 + j) * N + c] = acc[mi][ni][j] + bs;
    }
  }
}

// ---------------------------------------------------------------------------
extern "C" void kernel_launch(void* const* d_in, const int* in_sizes, int n_in,
                              void* d_out, int out_size, void* d_ws, size_t ws_size,
                              hipStream_t stream)
{
  const float* value = (const float*)d_in[0];
  const float* key   = (const float*)d_in[1];
  const float* query = (const float*)d_in[2];
  const float* Wv  = (const float*)d_in[3];
  const float* bv  = (const float*)d_in[4];
  const float* Wk  = (const float*)d_in[5];
  const float* bk  = (const float*)d_in[6];
  const float* Wq  = (const float*)d_in[7];
  const float* bq  = (const float*)d_in[8];
  const float* Wfc = (const float*)d_in[9];
  const float* bfc = (const float*)d_in[10];
  float* out = (float*)d_out;

  char* ws = (char*)d_ws;
  __hip_bfloat16* Xb   = (__hip_bfloat16*)ws;                          // 32 MiB
  __hip_bfloat16* Wfcb = (__hip_bfloat16*)(ws + 33554432);             // 2 MiB
  __hip_bfloat16* Wqb  = (__hip_bfloat16*)(ws + 33554432 + 2097152);   // 8 KiB
  __hip_bfloat16* Wkb  = Wqb + 4096;
  __hip_bfloat16* Wvb  = Wkb + 4096;

  prep_kernel<<<4096, 256, 0, stream>>>(Wq, Wk, Wv, Wfc, Wqb, Wkb, Wvb, Wfcb);
  attn_kernel<<<1024, 256, 0, stream>>>(value, key, query, Wvb, Wkb, Wqb,
                                        bv, bk, bq, Xb);
  gemm_kernel<<<1024, 256, 0, stream>>>(Xb, Wfcb, bfc, out);
}

// Round 4
// 109.602 us; speedup vs baseline: 2.0542x; 1.0641x over previous
//
#include <hip/hip_runtime.h>
#include <hip/hip_bf16.h>

#define AS1 __attribute__((address_space(1)))
#define AS3 __attribute__((address_space(3)))

typedef __attribute__((ext_vector_type(8))) short bf16x8v;   // 8 bf16 (4 VGPRs)
typedef __attribute__((ext_vector_type(4))) short bf16x4v;   // 4 bf16 (2 VGPRs)
typedef __attribute__((ext_vector_type(4))) float f32x4;

#define MFMA32 __builtin_amdgcn_mfma_f32_16x16x32_bf16
#define MFMA16 __builtin_amdgcn_mfma_f32_16x16x16bf16_1k

__device__ __forceinline__ short f2bf(float f) {
  __hip_bfloat16 h = __float2bfloat16(f);          // RNE
  return *reinterpret_cast<short*>(&h);
}
__device__ __forceinline__ bf16x4v cvt4(f32x4 v) {
  bf16x4v r; r[0]=f2bf(v[0]); r[1]=f2bf(v[1]); r[2]=f2bf(v[2]); r[3]=f2bf(v[3]);
  return r;
}
__device__ __forceinline__ bf16x8v cvt8(float4 a, float4 b) {
  bf16x8v r;
  r[0]=f2bf(a.x); r[1]=f2bf(a.y); r[2]=f2bf(a.z); r[3]=f2bf(a.w);
  r[4]=f2bf(b.x); r[5]=f2bf(b.y); r[6]=f2bf(b.z); r[7]=f2bf(b.w);
  return r;
}

// ---------------------------------------------------------------------------
// prep: bf16 copies of Wq/Wk/Wv + Wfc.
// ---------------------------------------------------------------------------
__global__ void prep_kernel(const float* __restrict__ Wq, const float* __restrict__ Wk,
                            const float* __restrict__ Wv, const float* __restrict__ Wfc,
                            __hip_bfloat16* __restrict__ Wqb, __hip_bfloat16* __restrict__ Wkb,
                            __hip_bfloat16* __restrict__ Wvb, __hip_bfloat16* __restrict__ Wfcb)
{
  int i = blockIdx.x * blockDim.x + threadIdx.x;
  if (i < 64 * 64) {
    Wqb[i] = __float2bfloat16(Wq[i]);
    Wkb[i] = __float2bfloat16(Wk[i]);
    Wvb[i] = __float2bfloat16(Wv[i]);
  }
  for (int j = i; j < 1024 * 1024; j += gridDim.x * blockDim.x)
    Wfcb[j] = __float2bfloat16(Wfc[j]);
}

// ---------------------------------------------------------------------------
// attn_kernel: 1 wave streams 8 tokens. Q/K rows staged CONTIGUOUSLY into
// per-wave private LDS slices via global_load_lds (1KB/instr, async, dbuf),
// fragments read from LDS. V prefetched depth-1 via registers. Zero barriers;
// counted vmcnt only. 512 blocks x 4 waves, 64KB LDS/block -> 2 blocks/CU.
// ---------------------------------------------------------------------------
struct TokV { float4 va0, vb0, va1, vb1; float4 va2, vb2, va3, vb3; float4 va4, vb4, va5, vb5; };

__global__ __launch_bounds__(256) void attn_kernel(
    const float* __restrict__ Vin, const float* __restrict__ Kin,
    const float* __restrict__ Qin,
    const __hip_bfloat16* __restrict__ Wvb, const __hip_bfloat16* __restrict__ Wkb,
    const __hip_bfloat16* __restrict__ Wqb,
    const float* __restrict__ bv, const float* __restrict__ bk,
    const float* __restrict__ bq,
    __hip_bfloat16* __restrict__ Xout)
{
  __shared__ float lds[4][2][2048];   // [wave][slot][Q:0..1023 | K:1024..2047]
  const int wid = threadIdx.x >> 6, lane = threadIdx.x & 63;
  const int lo = lane & 15, hi = lane >> 4;
  constexpr int NT = 8;
  const int tok0 = (blockIdx.x * 4 + wid) * NT;
  const int fo = lo * 64 + hi * 8;          // fragment float-offset in a row

  // weight fragments, once per wave
  bf16x8v wqf[4][2], wkf[4][2], wvf[4][2];
#pragma unroll
  for (int i = 0; i < 4; ++i)
#pragma unroll
    for (int ks = 0; ks < 2; ++ks) {
      const int off = (i * 16 + lo) * 64 + ks * 32 + hi * 8;
      wqf[i][ks] = *(const bf16x8v*)(Wqb + off);
      wkf[i][ks] = *(const bf16x8v*)(Wkb + off);
      wvf[i][ks] = *(const bf16x8v*)(Wvb + off);
    }
  float4 bq4[4], bk4[4]; float bvv[4];
#pragma unroll
  for (int i = 0; i < 4; ++i) {
    bq4[i] = *(const float4*)(bq + i * 16 + hi * 4);
    bk4[i] = *(const float4*)(bk + i * 16 + hi * 4);
    bvv[i] = bv[i * 16 + lo];
  }

  auto stageQK = [&](int n) {               // 8 x global_load_lds, 1KB each
    const size_t tb = (size_t)(tok0 + n) * 1024;
    float* dq = &lds[wid][n & 1][0];
    float* dk = &lds[wid][n & 1][1024];
    const float* gq = Qin + tb + lane * 4;
    const float* gk = Kin + tb + lane * 4;
#pragma unroll
    for (int i = 0; i < 4; ++i)
      __builtin_amdgcn_global_load_lds((const AS1 void*)(gq + i * 256),
                                       (AS3 void*)(dq + i * 256), 16, 0, 0);
#pragma unroll
    for (int i = 0; i < 4; ++i)
      __builtin_amdgcn_global_load_lds((const AS1 void*)(gk + i * 256),
                                       (AS3 void*)(dk + i * 256), 16, 0, 0);
  };

  auto loadV = [&](int n, TokV& T) {        // 12 x dwordx4 (register path)
    const float* vp = Vin + (size_t)(tok0 + n) * 1024 + fo;
    T.va0 = *(const float4*)(vp);      T.vb0 = *(const float4*)(vp + 4);
    T.va1 = *(const float4*)(vp + 32); T.vb1 = *(const float4*)(vp + 36);
    // pad slots unused; keep 12 loads only:
    T.va2 = T.va0; T.vb2 = T.vb0; T.va3 = T.va1; T.vb3 = T.vb1;
    T.va4 = T.va0; T.vb4 = T.vb0; T.va5 = T.va1; T.vb5 = T.vb1;
  };

  // prologue
  stageQK(0);
  stageQK(1);
  TokV V;
  {
    const float* vp = Vin + (size_t)tok0 * 1024 + fo;
    V.va0 = *(const float4*)(vp);      V.vb0 = *(const float4*)(vp + 4);
    V.va1 = *(const float4*)(vp + 32); V.vb1 = *(const float4*)(vp + 36);
  }

#pragma unroll
  for (int n = 0; n < NT; ++n) {
    // --- wait for QK(n) staged (drain to the 20/12 newest vmem ops) ---
    if (n < NT - 1) { asm volatile("s_waitcnt vmcnt(20)" ::: "memory"); }
    else           { asm volatile("s_waitcnt vmcnt(12)" ::: "memory"); }
    __builtin_amdgcn_sched_barrier(0);

    const float* qs = &lds[wid][n & 1][0];
    const float* ksrc = &lds[wid][n & 1][1024];
    float4 qa0 = *(const float4*)(qs + fo),      qb0 = *(const float4*)(qs + fo + 4);
    float4 qa1 = *(const float4*)(qs + fo + 32), qb1 = *(const float4*)(qs + fo + 36);
    float4 ka0 = *(const float4*)(ksrc + fo),      kb0 = *(const float4*)(ksrc + fo + 4);
    float4 ka1 = *(const float4*)(ksrc + fo + 32), kb1 = *(const float4*)(ksrc + fo + 36);
    bf16x8v xq0 = cvt8(qa0, qb0), xq1 = cvt8(qa1, qb1);
    bf16x8v xk0 = cvt8(ka0, kb0), xk1 = cvt8(ka1, kb1);

    // projections qT/kT: per d-block i, C row = d = i*16+hi*4+j, col = h = lo
    f32x4 qt[4], kt[4];
#pragma unroll
    for (int i = 0; i < 4; ++i) {
      f32x4 aq = { bq4[i].x, bq4[i].y, bq4[i].z, bq4[i].w };
      aq = MFMA32(wqf[i][0], xq0, aq, 0, 0, 0);
      aq = MFMA32(wqf[i][1], xq1, aq, 0, 0, 0);
      qt[i] = aq;
      f32x4 ak = { bk4[i].x, bk4[i].y, bk4[i].z, bk4[i].w };
      ak = MFMA32(wkf[i][0], xk0, ak, 0, 0, 0);
      ak = MFMA32(wkf[i][1], xk1, ak, 0, 0, 0);
      kt[i] = ak;
    }

    // E' = K@Q^T over 4 d-blocks; e[j] = E[h=lo][g=hi*4+j]
    f32x4 ea = { 0.f, 0.f, 0.f, 0.f }, eb = { 0.f, 0.f, 0.f, 0.f };
    ea = MFMA16(cvt4(kt[0]), cvt4(qt[0]), ea, 0, 0, 0);
    eb = MFMA16(cvt4(kt[1]), cvt4(qt[1]), eb, 0, 0, 0);
    ea = MFMA16(cvt4(kt[2]), cvt4(qt[2]), ea, 0, 0, 0);
    eb = MFMA16(cvt4(kt[3]), cvt4(qt[3]), eb, 0, 0, 0);
    f32x4 e = ea + eb;

    // softmax over g
    float mx = fmaxf(fmaxf(e[0], e[1]), fmaxf(e[2], e[3]));
    mx = fmaxf(mx, __shfl_xor(mx, 16));
    mx = fmaxf(mx, __shfl_xor(mx, 32));
    float p0 = __expf((e[0] - mx) * 0.125f);
    float p1 = __expf((e[1] - mx) * 0.125f);
    float p2 = __expf((e[2] - mx) * 0.125f);
    float p3 = __expf((e[3] - mx) * 0.125f);
    float s = p0 + p1 + p2 + p3;
    s += __shfl_xor(s, 16);
    s += __shfl_xor(s, 32);
    const float inv = 1.0f / s;
    bf16x4v pa;
    pa[0] = f2bf(p0 * inv); pa[1] = f2bf(p1 * inv);
    pa[2] = f2bf(p2 * inv); pa[3] = f2bf(p3 * inv);

    // v-projection (V from registers; compiler inserts its own vmcnt wait)
    bf16x8v xv0 = cvt8(V.va0, V.vb0), xv1 = cvt8(V.va1, V.vb1);
    f32x4 vc[4];
#pragma unroll
    for (int i = 0; i < 4; ++i) {
      f32x4 av = { bvv[i], bvv[i], bvv[i], bvv[i] };
      av = MFMA32(xv0, wvf[i][0], av, 0, 0, 0);
      av = MFMA32(xv1, wvf[i][1], av, 0, 0, 0);
      vc[i] = av;
    }

    // O = P @ v ; D row = h = hi*4+j, col = dv = ni*16+lo
    __hip_bfloat16* xo = Xout + (size_t)(tok0 + n) * 1024 + (size_t)hi * 4 * 64 + lo;
#pragma unroll
    for (int ni = 0; ni < 4; ++ni) {
      f32x4 z = { 0.f, 0.f, 0.f, 0.f };
      z = MFMA16(pa, cvt4(vc[ni]), z, 0, 0, 0);
#pragma unroll
      for (int j = 0; j < 4; ++j)
        xo[j * 64 + ni * 16] = __float2bfloat16(z[j]);
    }

    asm volatile("" ::: "memory");          // order: stores | V loads | stage
    if (n + 1 < NT) {
      const float* vp = Vin + (size_t)(tok0 + n + 1) * 1024 + fo;
      V.va0 = *(const float4*)(vp);      V.vb0 = *(const float4*)(vp + 4);
      V.va1 = *(const float4*)(vp + 32); V.vb1 = *(const float4*)(vp + 36);
    }
    asm volatile("" ::: "memory");
    if (n + 2 < NT) {
      asm volatile("s_waitcnt lgkmcnt(0)" ::: "memory");  // LDS reads done
      __builtin_amdgcn_sched_barrier(0);
      stageQK(n + 2);
    }
    asm volatile("" ::: "memory");
  }
}

// ---------------------------------------------------------------------------
// gemm_kernel: C = X(bf16) @ Wfc^T + bfc. bm/bn decode swapped so the 8
// blocks sharing an A-panel land on one XCD (bid%8 == bm%8) -> A reused in L2.
// ---------------------------------------------------------------------------
__global__ __launch_bounds__(256) void gemm_kernel(
    const __hip_bfloat16* __restrict__ A,
    const __hip_bfloat16* __restrict__ B,
    const float* __restrict__ bias, float* __restrict__ C)
{
  constexpr int K = 1024, N = 1024;
  __shared__ __hip_bfloat16 Asm[128 * 64];
  __shared__ __hip_bfloat16 Bsm[128 * 64];
  const int tid = threadIdx.x, wid = tid >> 6, lane = tid & 63;
  const int bm = blockIdx.x & 127, bn = blockIdx.x >> 7;
  const int m0 = bm * 128, n0 = bn * 128;
  const int wr = wid >> 1, wc = wid & 1;

  f32x4 acc[4][4];
#pragma unroll
  for (int i = 0; i < 4; ++i)
#pragma unroll
    for (int j = 0; j < 4; ++j) acc[i][j] = (f32x4){0.f, 0.f, 0.f, 0.f};

  const int lrow = lane >> 3;
  const int gcol = ((lane & 7) ^ lrow) * 8;

  for (int kt = 0; kt < K / 64; ++kt) {
    const int k0 = kt * 64;
    __syncthreads();
#pragma unroll
    for (int c = 0; c < 4; ++c) {
      const int ca = wid * 4 + c;
      const int row = ca * 8 + lrow;
      __builtin_amdgcn_global_load_lds(
          (const AS1 void*)(A + (size_t)(m0 + row) * K + k0 + gcol),
          (AS3 void*)((char*)Asm + ca * 1024), 16, 0, 0);
      __builtin_amdgcn_global_load_lds(
          (const AS1 void*)(B + (size_t)(n0 + row) * K + k0 + gcol),
          (AS3 void*)((char*)Bsm + ca * 1024), 16, 0, 0);
    }
    asm volatile("s_waitcnt vmcnt(0)" ::: "memory");
    __syncthreads();

#pragma unroll
    for (int ks = 0; ks < 2; ++ks) {
      bf16x8v af[4], bfr[4];
#pragma unroll
      for (int mi = 0; mi < 4; ++mi) {
        const int arow = wr * 64 + mi * 16 + (lane & 15);
        const int slot = (ks * 4 + (lane >> 4)) ^ (arow & 7);
        af[mi] = *(const bf16x8v*)((const char*)Asm + arow * 128 + slot * 16);
      }
#pragma unroll
      for (int ni = 0; ni < 4; ++ni) {
        const int brow = wc * 64 + ni * 16 + (lane & 15);
        const int slot = (ks * 4 + (lane >> 4)) ^ (brow & 7);
        bfr[ni] = *(const bf16x8v*)((const char*)Bsm + brow * 128 + slot * 16);
      }
#pragma unroll
      for (int mi = 0; mi < 4; ++mi)
#pragma unroll
        for (int ni = 0; ni < 4; ++ni)
          acc[mi][ni] = __builtin_amdgcn_mfma_f32_16x16x32_bf16(
              af[mi], bfr[ni], acc[mi][ni], 0, 0, 0);
    }
  }

#pragma unroll
  for (int mi = 0; mi < 4; ++mi) {
    const int r0 = m0 + wr * 64 + mi * 16 + (lane >> 4) * 4;
#pragma unroll
    for (int ni = 0; ni < 4; ++ni) {
      const int c = n0 + wc * 64 + ni * 16 + (lane & 15);
      const float bs = bias[c];
#pragma unroll
      for (int j = 0; j < 4; ++j)
        C[(size_t)(r0 + j) * N + c] = acc[mi][ni][j] + bs;
    }
  }
}

// ---------------------------------------------------------------------------
extern "C" void kernel_launch(void* const* d_in, const int* in_sizes, int n_in,
                              void* d_out, int out_size, void* d_ws, size_t ws_size,
                              hipStream_t stream)
{
  const float* value = (const float*)d_in[0];
  const float* key   = (const float*)d_in[1];
  const float* query = (const float*)d_in[2];
  const float* Wv  = (const float*)d_in[3];
  const float* bv  = (const float*)d_in[4];
  const float* Wk  = (const float*)d_in[5];
  const float* bk  = (const float*)d_in[6];
  const float* Wq  = (const float*)d_in[7];
  const float* bq  = (const float*)d_in[8];
  const float* Wfc = (const float*)d_in[9];
  const float* bfc = (const float*)d_in[10];
  float* out = (float*)d_out;

  char* ws = (char*)d_ws;
  __hip_bfloat16* Xb   = (__hip_bfloat16*)ws;                          // 32 MiB
  __hip_bfloat16* Wfcb = (__hip_bfloat16*)(ws + 33554432);             // 2 MiB
  __hip_bfloat16* Wqb  = (__hip_bfloat16*)(ws + 33554432 + 2097152);   // 8 KiB
  __hip_bfloat16* Wkb  = Wqb + 4096;
  __hip_bfloat16* Wvb  = Wkb + 4096;

  prep_kernel<<<4096, 256, 0, stream>>>(Wq, Wk, Wv, Wfc, Wqb, Wkb, Wvb, Wfcb);
  attn_kernel<<<512, 256, 0, stream>>>(value, key, query, Wvb, Wkb, Wqb,
                                       bv, bk, bq, Xb);
  gemm_kernel<<<1024, 256, 0, stream>>>(Xb, Wfcb, bfc, out);
}